// Round 12
// baseline (50745.547 us; speedup 1.0000x reference)
//
#include <hip/hip_runtime.h>
#include <hip/hip_bf16.h>

#define T_SEQ 10240
#define GRU_W 8

typedef short bf16x8 __attribute__((ext_vector_type(8)));
typedef float f32x4 __attribute__((ext_vector_type(4)));

__device__ __forceinline__ float bf2f(unsigned short u) {
    return __uint_as_float(((unsigned int)u) << 16);
}
__device__ __forceinline__ unsigned short f2bf(float f) {
    __hip_bfloat16 h = __float2bfloat16(f);
    return *reinterpret_cast<unsigned short*>(&h);
}

// ---------------- mel upsampling ----------------
__global__ void upsample_kernel(const float* __restrict__ in, float* __restrict__ out,
                                const float* __restrict__ wk,
                                int B, int Tin, int Tout, int shift, int taps)
{
    int idx = blockIdx.x * blockDim.x + threadIdx.x;
    int total = B * Tout * 80;
    if (idx >= total) return;
    int m = idx % 80;
    int r = idx / 80;
    int t = r % Tout;
    int b = r / Tout;
    int s = taps >> 1;
    float acc = 0.f;
    for (int d = -s; d <= s; ++d) {
        int i = t + d;
        if (i >= 0 && i < Tout)
            acc += in[((size_t)b * Tin + (i >> shift)) * 80 + m] * wk[d + s];
    }
    out[idx] = acc;
}

// ---------------- conditioning net ----------------
__global__ __launch_bounds__(128) void conv0_kernel(
    const float* __restrict__ mels, const float* __restrict__ w,
    const float* __restrict__ g, const float* __restrict__ b,
    const float* __restrict__ m_, const float* __restrict__ v_,
    float* __restrict__ a)
{
    __shared__ float xin[400];
    int bt = blockIdx.x;
    int bb = bt / 40, t = bt % 40;
    int c = threadIdx.x;
    for (int idx = c; idx < 400; idx += 128)
        xin[idx] = mels[((size_t)bb * 44 + t + idx / 80) * 80 + (idx % 80)];
    __syncthreads();
    float s = 0.f;
    for (int q = 0; q < 400; ++q) s += xin[q] * w[q * 128 + c];
    s = (s - m_[c]) * rsqrtf(v_[c] + 1e-3f) * g[c] + b[c];
    a[bt * 128 + c] = fmaxf(s, 0.f);
}

__global__ __launch_bounds__(128) void resblock_kernel(
    const float* __restrict__ W1, const float* __restrict__ W2,
    const float* __restrict__ g1, const float* __restrict__ b1,
    const float* __restrict__ m1, const float* __restrict__ v1,
    const float* __restrict__ g2, const float* __restrict__ b2,
    const float* __restrict__ m2, const float* __restrict__ v2,
    float* __restrict__ a)
{
    __shared__ float ain[128], y1[128];
    int tok = blockIdx.x;
    int c = threadIdx.x;
    ain[c] = a[tok * 128 + c];
    __syncthreads();
    float s = 0.f;
    #pragma unroll 8
    for (int k = 0; k < 128; ++k) s += ain[k] * W1[k * 128 + c];
    s = (s - m1[c]) * rsqrtf(v1[c] + 1e-3f) * g1[c] + b1[c];
    y1[c] = fmaxf(s, 0.f);
    __syncthreads();
    float s2 = 0.f;
    #pragma unroll 8
    for (int k = 0; k < 128; ++k) s2 += y1[k] * W2[k * 128 + c];
    s2 = (s2 - m2[c]) * rsqrtf(v2[c] + 1e-3f) * g2[c] + b2[c];
    a[tok * 128 + c] = ain[c] + s2;
}

__global__ __launch_bounds__(128) void outmat_kernel(
    const float* __restrict__ W, const float* __restrict__ bias,
    const float* __restrict__ a, float* __restrict__ out)
{
    __shared__ float ain[128];
    int tok = blockIdx.x;
    int c = threadIdx.x;
    ain[c] = a[tok * 128 + c];
    __syncthreads();
    float s = 0.f;
    #pragma unroll 8
    for (int k = 0; k < 128; ++k) s += ain[k] * W[k * 128 + c];
    out[tok * 128 + c] = s + bias[c];
}

// ---------------- scalar GEMM (mode 0 only: Wi, K=113 gather) ----------------
__global__ __launch_bounds__(256) void gemm_big(
    int N, int K,
    const float* __restrict__ W, const float* __restrict__ bias1,
    const float* __restrict__ audio, const float* __restrict__ melsup,
    const float* __restrict__ cond, float* __restrict__ outF)
{
    __shared__ float As[16][68];
    __shared__ float Bs[16][68];
    const int tid = threadIdx.x;
    const int row0 = blockIdx.y * 64;
    const int col0 = blockIdx.x * 64;
    const int tx = tid & 15, ty = tid >> 4;
    float acc[4][4] = {};
    const int nkt = (K + 15) >> 4;
    for (int kt = 0; kt < nkt; ++kt) {
        const int kb = kt << 4;
        #pragma unroll
        for (int l = 0; l < 4; ++l) {
            int k = (tid >> 6) + l * 4;
            int m = tid & 63;
            float bv = 0.f;
            if (kb + k < K) bv = W[(size_t)(kb + k) * N + col0 + m];
            Bs[k][m] = bv;
            int row = row0 + m;
            int b = row / T_SEQ;
            int t = row - b * T_SEQ;
            int kk = kb + k;
            float av = 0.f;
            if (kk < K) {
                if (kk == 0) av = audio[(size_t)b * (T_SEQ + 1) + t];
                else if (kk < 81) av = melsup[((size_t)b * 11264 + 512 + t) * 80 + (kk - 1)];
                else av = cond[((size_t)b * 40 + (t >> 8)) * 128 + (kk - 81)];
            }
            As[k][m] = av;
        }
        __syncthreads();
        #pragma unroll
        for (int k = 0; k < 16; ++k) {
            float a0 = As[k][(ty << 2) + 0], a1 = As[k][(ty << 2) + 1];
            float a2 = As[k][(ty << 2) + 2], a3 = As[k][(ty << 2) + 3];
            float b0 = Bs[k][(tx << 2) + 0], b1 = Bs[k][(tx << 2) + 1];
            float b2 = Bs[k][(tx << 2) + 2], b3 = Bs[k][(tx << 2) + 3];
            acc[0][0] += a0 * b0; acc[0][1] += a0 * b1; acc[0][2] += a0 * b2; acc[0][3] += a0 * b3;
            acc[1][0] += a1 * b0; acc[1][1] += a1 * b1; acc[1][2] += a1 * b2; acc[1][3] += a1 * b3;
            acc[2][0] += a2 * b0; acc[2][1] += a2 * b1; acc[2][2] += a2 * b2; acc[2][3] += a2 * b3;
            acc[3][0] += a3 * b0; acc[3][1] += a3 * b1; acc[3][2] += a3 * b2; acc[3][3] += a3 * b3;
        }
        __syncthreads();
    }
    #pragma unroll
    for (int i = 0; i < 4; ++i) {
        int row = row0 + (ty << 2) + i;
        #pragma unroll
        for (int jt = 0; jt < 4; ++jt) {
            int col = col0 + (tx << 2) + jt;
            outF[(size_t)row * N + col] = acc[i][jt] + bias1[col];
        }
    }
}

// ---------------- pack W (f32 [K][N]) -> bf16 col-major [N][576], zero-padded K ----------------
__global__ __launch_bounds__(256) void pack_wt_kernel(const float* __restrict__ W,
                                                      unsigned short* __restrict__ out,
                                                      int K, int N)
{
    int idx = blockIdx.x * 256 + threadIdx.x;
    if (idx >= N * 576) return;
    int n = idx / 576, kp = idx % 576;
    out[idx] = (kp < K) ? f2bf(W[(size_t)kp * N + n]) : (unsigned short)0;
}

// ---------------- MFMA GEMM for modes 1-4 ----------------
__global__ __launch_bounds__(256) void gemm_mfma(
    int mode, int K,
    const unsigned short* __restrict__ Wt,   // [N][576] bf16
    const float* __restrict__ bias1,
    const float* __restrict__ bias2,
    const float* __restrict__ cond,
    const float* __restrict__ xA,            // (40960,512) f32
    const float* __restrict__ resid,
    float* __restrict__ outF,
    __hip_bfloat16* __restrict__ outB)
{
    __shared__ alignas(16) unsigned short A_sh[64][72];
    __shared__ alignas(16) unsigned short B_sh[128][72];
    const int tid = threadIdx.x;
    const int row0 = blockIdx.y * 64;
    const int col0 = blockIdx.x * 128;
    const int wv = tid >> 6, l = tid & 63;

    f32x4 acc[4][2] = {};
    const int nkt = (K + 63) >> 6;
    for (int it = 0; it < nkt; ++it) {
        const int kb = it << 6;
        {
            const int r = tid >> 2, q = tid & 3;
            const int row = row0 + r;
            unsigned short tmp[16];
            if (kb + 64 <= 512) {
                const float* src = xA + (size_t)row * 512 + kb + q * 16;
                #pragma unroll
                for (int e = 0; e < 16; e += 4) {
                    float4 v = *reinterpret_cast<const float4*>(src + e);
                    tmp[e + 0] = f2bf(v.x); tmp[e + 1] = f2bf(v.y);
                    tmp[e + 2] = f2bf(v.z); tmp[e + 3] = f2bf(v.w);
                }
            } else {
                const int b = row / T_SEQ, trow = row - b * T_SEQ;
                const int co = (mode == 2) ? 32 : (mode == 3) ? 64 : 96;
                const float* cp = cond + ((size_t)b * 40 + (trow >> 8)) * 128 + co;
                #pragma unroll
                for (int e = 0; e < 16; ++e) {
                    int k = kb + q * 16 + e;
                    float v = 0.f;
                    if (k < 512) v = xA[(size_t)row * 512 + k];
                    else if (k < K) v = cp[k - 512];
                    tmp[e] = f2bf(v);
                }
            }
            #pragma unroll
            for (int e = 0; e < 16; e += 8)
                *reinterpret_cast<uint4*>(&A_sh[r][q * 16 + e]) =
                    *reinterpret_cast<const uint4*>(&tmp[e]);
        }
        {
            const int c = tid >> 1, half = tid & 1;
            const unsigned short* src = Wt + (size_t)(col0 + c) * 576 + kb + half * 32;
            #pragma unroll
            for (int e = 0; e < 32; e += 8)
                *reinterpret_cast<uint4*>(&B_sh[c][half * 32 + e]) =
                    *reinterpret_cast<const uint4*>(src + e);
        }
        __syncthreads();
        const int rsel = l & 15, q = l >> 4;
        #pragma unroll
        for (int ks = 0; ks < 2; ++ks) {
            bf16x8 a[4], b[2];
            #pragma unroll
            for (int mf = 0; mf < 4; ++mf)
                a[mf] = *reinterpret_cast<const bf16x8*>(
                    &A_sh[mf * 16 + rsel][ks * 32 + q * 8]);
            #pragma unroll
            for (int nf = 0; nf < 2; ++nf)
                b[nf] = *reinterpret_cast<const bf16x8*>(
                    &B_sh[wv * 32 + nf * 16 + rsel][ks * 32 + q * 8]);
            #pragma unroll
            for (int mf = 0; mf < 4; ++mf)
                #pragma unroll
                for (int nf = 0; nf < 2; ++nf)
                    acc[mf][nf] = __builtin_amdgcn_mfma_f32_16x16x32_bf16(
                        a[mf], b[nf], acc[mf][nf], 0, 0, 0);
        }
        __syncthreads();
    }
    const int rsel = l & 15, q = l >> 4;
    #pragma unroll
    for (int mf = 0; mf < 4; ++mf) {
        #pragma unroll
        for (int nf = 0; nf < 2; ++nf) {
            #pragma unroll
            for (int i = 0; i < 4; ++i) {
                int row = row0 + mf * 16 + q * 4 + i;
                int col = col0 + wv * 32 + nf * 16 + rsel;
                float v = acc[mf][nf][i] + bias1[col];
                if (mode <= 2) {
                    if (col < 1024) v += bias2[col];
                    outB[(size_t)row * 1536 + col] = __float2bfloat16(v);
                } else {
                    v = fmaxf(v, 0.f) + resid[(size_t)row * 512 + col];
                    outF[(size_t)row * 512 + col] = v;
                }
            }
        }
    }
}

// ---------------- pack Wh -> per-wave MFMA B-fragments (r7 mapping) ----------------
__global__ __launch_bounds__(256) void pack_wh_kernel(const float* __restrict__ Wh,
                                                      unsigned short* __restrict__ out)
{
    int gid = blockIdx.x * 256 + threadIdx.x;     // < 98304
    int l = gid & 63;
    int idx = gid >> 6;
    int kt = idx & 15; idx >>= 4;
    int ntL = idx & 1; idx >>= 1;
    int w = idx % 6;
    int wg = idx / 6;
    int nt = 2 * w + ntL;
    int g = nt >> 2, u = nt & 3;
    int n = g * 512 + wg * 64 + u * 16 + (l & 15);
    int k0 = kt * 32 + (l >> 4) * 8;
    unsigned short* dst = out + (size_t)gid * 8;
    #pragma unroll
    for (int i = 0; i < 8; ++i)
        dst[i] = f2bf(Wh[(size_t)(k0 + i) * 1536 + n]);
}

// ---------------- 8-WG MFMA GRU: full role separation ----------------
// 512 thr = 8 waves.
// Waves 0-3: POLL (8 pairs each; their vmcnt = only 4 poll loads) + ds_write
//            h_sh + MFMA. NO stores -> detect wait never drains stores.
// Waves 4-5: MFMA + GATES + publish + xio stores (store-only sink; their
//            vmcnt is never waited on). Each lane handles 2 batches.
// Waves 6-7: T14 staging of xp/xv (write held t+1, then issue t+2 loads)
//            into triple-buffered LDS.
// 2 barriers/step; h-ring = {tag16|bf16} 4B relaxed agent atomics, ping-pong.
__global__ __launch_bounds__(512, 2) void gru_mfma8(
    const unsigned short* __restrict__ wpack,
    const float* __restrict__ bh,
    const __hip_bfloat16* __restrict__ xp,      // (4*T,1536) bf16
    float* __restrict__ xio,                    // (4*T,512) f32 in x / out x+h
    unsigned int* __restrict__ hpair,           // [2][4][512] u32, memset 0
    int T)
{
    __shared__ alignas(16) unsigned short h_sh[16 * 512];      // 16 KB
    __shared__ alignas(16) unsigned short xp_sh[3][4][3][64];  // 4.5 KB
    __shared__ alignas(16) float xv_sh[3][4][64];              // 3 KB
    __shared__ alignas(16) float acc_sh[12][16][4];            // 3 KB

    const int tid = threadIdx.x;
    const int wg = blockIdx.x;
    const int w = tid >> 6;
    const int l = tid & 63;

    // zero h_sh (pad rows 4-15 must stay 0)
    {
        uint4* z = reinterpret_cast<uint4*>(h_sh);
        for (int i = tid; i < 1024; i += 512) z[i] = make_uint4(0, 0, 0, 0);
    }

    // weights (waves 0-5)
    bf16x8 wf[2][16];
    if (w < 6) {
        const bf16x8* wp = reinterpret_cast<const bf16x8*>(wpack);
        const int base = (wg * 6 + w) * 2 * 16 * 64;
        #pragma unroll
        for (int n = 0; n < 2; ++n)
            #pragma unroll
            for (int kt = 0; kt < 16; ++kt)
                wf[n][kt] = wp[base + (n * 16 + kt) * 64 + l];
    }

    // gate lanes: waves 4-5, each lane owns unit jl for 2 batches
    float bhh = 0.f;
    float hprev[2] = {0.f, 0.f};
    if (w == 4 || w == 5) bhh = bh[1024 + wg * 64 + ((tid - 256) & 63)];

    // ---- stage helpers (waves 6-7; xc in [0,128)) ----
    const int xc = tid - 384;
    uint4 hold_a = make_uint4(0, 0, 0, 0), hold_b = make_uint4(0, 0, 0, 0);
    #define STAGE_LOAD(c, t, dstv)                                              \
        { int c_ = (c);                                                         \
          if (c_ < 96) { int g_ = c_ / 32, b_ = (c_ % 32) / 8, s_ = c_ % 8;     \
            dstv = *reinterpret_cast<const uint4*>(                             \
                reinterpret_cast<const unsigned short*>(xp) +                   \
                ((size_t)b_ * T + (t)) * 1536 + g_ * 512 + wg * 64 + s_ * 8);   \
          } else { int d_ = c_ - 96, b_ = d_ >> 4, s_ = d_ & 15;                \
            dstv = *reinterpret_cast<const uint4*>(                             \
                xio + ((size_t)b_ * T + (t)) * 512 + wg * 64 + s_ * 4); } }
    #define STAGE_WRITE(c, buf, v)                                              \
        { int c_ = (c);                                                         \
          if (c_ < 96) { int g_ = c_ / 32, b_ = (c_ % 32) / 8, s_ = c_ % 8;     \
            *reinterpret_cast<uint4*>(&xp_sh[buf][b_][g_][s_ * 8]) = v;         \
          } else { int d_ = c_ - 96, b_ = d_ >> 4, s_ = d_ & 15;                \
            *reinterpret_cast<uint4*>(&xv_sh[buf][b_][s_ * 4]) = v; } }

    if (w >= 6) {
        uint4 v;
        STAGE_LOAD(xc, 0, v); STAGE_WRITE(xc, 0, v);
        if (xc < 32) { STAGE_LOAD(128 + xc, 0, v); STAGE_WRITE(128 + xc, 0, v); }
        if (T > 1) {
            STAGE_LOAD(xc, 1, hold_a);
            if (xc < 32) STAGE_LOAD(128 + xc, 1, hold_b);
        }
    }
    __syncthreads();

    const unsigned long long* hp64 = reinterpret_cast<const unsigned long long*>(hpair);
    const int pb = tid >> 6;                      // poll batch (waves 0-3)
    const int pchunk = (tid & 63) ^ (pb & 7);     // swizzled 16B chunk

    for (int t = 0; t < T; ++t) {
        const int cur = t & 1;
        const int bu = t % 3;

        if (tid < 256) {
            // ---- poll own 8 pairs (4 independent 8B loads); store-free wave ----
            const unsigned long long* src = hp64 + (size_t)cur * 1024 + tid * 4;
            const unsigned tg = (unsigned)t & 0xffffu;
            unsigned long long u0 = __hip_atomic_load(src + 0, __ATOMIC_RELAXED, __HIP_MEMORY_SCOPE_AGENT);
            unsigned long long u1 = __hip_atomic_load(src + 1, __ATOMIC_RELAXED, __HIP_MEMORY_SCOPE_AGENT);
            unsigned long long u2 = __hip_atomic_load(src + 2, __ATOMIC_RELAXED, __HIP_MEMORY_SCOPE_AGENT);
            unsigned long long u3 = __hip_atomic_load(src + 3, __ATOMIC_RELAXED, __HIP_MEMORY_SCOPE_AGENT);
            while ((((unsigned)(u0 >> 16) & 0xffffu) != tg) | ((unsigned)(u0 >> 48) != tg) |
                   (((unsigned)(u1 >> 16) & 0xffffu) != tg) | ((unsigned)(u1 >> 48) != tg) |
                   (((unsigned)(u2 >> 16) & 0xffffu) != tg) | ((unsigned)(u2 >> 48) != tg) |
                   (((unsigned)(u3 >> 16) & 0xffffu) != tg) | ((unsigned)(u3 >> 48) != tg)) {
                __builtin_amdgcn_s_sleep(1);
                u0 = __hip_atomic_load(src + 0, __ATOMIC_RELAXED, __HIP_MEMORY_SCOPE_AGENT);
                u1 = __hip_atomic_load(src + 1, __ATOMIC_RELAXED, __HIP_MEMORY_SCOPE_AGENT);
                u2 = __hip_atomic_load(src + 2, __ATOMIC_RELAXED, __HIP_MEMORY_SCOPE_AGENT);
                u3 = __hip_atomic_load(src + 3, __ATOMIC_RELAXED, __HIP_MEMORY_SCOPE_AGENT);
            }
            uint4 wv;
            wv.x = (unsigned)(u0 & 0xffffull) | ((unsigned)((u0 >> 32) & 0xffffull) << 16);
            wv.y = (unsigned)(u1 & 0xffffull) | ((unsigned)((u1 >> 32) & 0xffffull) << 16);
            wv.z = (unsigned)(u2 & 0xffffull) | ((unsigned)((u2 >> 32) & 0xffffull) << 16);
            wv.w = (unsigned)(u3 & 0xffffull) | ((unsigned)((u3 >> 32) & 0xffffull) << 16);
            *reinterpret_cast<uint4*>(
                reinterpret_cast<char*>(h_sh) + pb * 1024 + pchunk * 16) = wv;
        } else if (w >= 6) {
            // ---- T14 staging: write held t+1, then issue t+2 loads ----
            if (t + 1 < T) {
                const int bn = (t + 1) % 3;
                STAGE_WRITE(xc, bn, hold_a);
                if (xc < 32) STAGE_WRITE(128 + xc, bn, hold_b);
            }
            if (t + 2 < T) {
                STAGE_LOAD(xc, t + 2, hold_a);
                if (xc < 32) STAGE_LOAD(128 + xc, t + 2, hold_b);
            }
        }
        __syncthreads();   // bar1: h_sh[t] + xp_sh[(t+1)%3] ordered

        if (w < 6) {
            f32x4 acc0 = {0, 0, 0, 0}, acc1 = {0, 0, 0, 0};
            const int rb = l & 15, q = l >> 4;
            #pragma unroll
            for (int kt = 0; kt < 16; ++kt) {
                bf16x8 afr = *reinterpret_cast<const bf16x8*>(
                    reinterpret_cast<const char*>(h_sh) + rb * 1024 +
                    ((((kt * 4 + q) ^ (rb & 7))) << 4));
                acc0 = __builtin_amdgcn_mfma_f32_16x16x32_bf16(afr, wf[0][kt], acc0, 0, 0, 0);
                acc1 = __builtin_amdgcn_mfma_f32_16x16x32_bf16(afr, wf[1][kt], acc1, 0, 0, 0);
            }
            if (l < 16) {
                *reinterpret_cast<f32x4*>(&acc_sh[2 * w][l][0]) = acc0;
                *reinterpret_cast<f32x4*>(&acc_sh[2 * w + 1][l][0]) = acc1;
            }
        }
        __syncthreads();   // bar2: acc_sh ready

        if (w == 4 || w == 5) {
            // ---- gates: 128 lanes x 2 batches; store-only sink waves ----
            const int g = tid - 256;              // 0..127
            const int jl = g & 63, j = wg * 64 + jl;
            const int u = jl >> 4, n16 = jl & 15;
            const int b0 = (g >> 6) * 2;
            #pragma unroll
            for (int i = 0; i < 2; ++i) {
                const int b = b0 + i;
                float az = acc_sh[u][n16][b];
                float ar = acc_sh[4 + u][n16][b];
                float ah = acc_sh[8 + u][n16][b];
                float xz = bf2f(xp_sh[bu][b][0][jl]);
                float xr = bf2f(xp_sh[bu][b][1][jl]);
                float xh = bf2f(xp_sh[bu][b][2][jl]);
                float xv = xv_sh[bu][b][jl];
                float z = 1.f / (1.f + __expf(-(xz + az)));
                float r = 1.f / (1.f + __expf(-(xr + ar)));
                float e2 = __expf(-2.f * (xh + r * (ah + bhh)));
                float hh = (1.f - e2) / (1.f + e2);
                float hn = z * hprev[i] + (1.f - z) * hh;
                hprev[i] = hn;
                unsigned hv = ((unsigned)((t + 1) & 0xffff) << 16) | (unsigned)f2bf(hn);
                __hip_atomic_store(hpair + (size_t)((t + 1) & 1) * 2048 + b * 512 + j, hv,
                                   __ATOMIC_RELAXED, __HIP_MEMORY_SCOPE_AGENT);
                xio[((size_t)b * T + t) * 512 + j] = xv + hn;
            }
        }
    }
    #undef STAGE_LOAD
    #undef STAGE_WRITE
}

// ---------------- final projection ----------------
__global__ __launch_bounds__(256) void wp_kernel(
    const float* __restrict__ x, const float* __restrict__ Wp,
    const float* __restrict__ bp, float* __restrict__ out)
{
    int r = threadIdx.x >> 5, c = threadIdx.x & 31;
    size_t row = (size_t)blockIdx.x * 8 + r;
    if (c >= 30) return;
    const float* xr = x + row * 512;
    float acc = 0.f;
    #pragma unroll 8
    for (int k = 0; k < 512; ++k) acc += xr[k] * Wp[k * 30 + c];
    out[row * 30 + c] = acc + bp[c];
}

extern "C" void kernel_launch(void* const* d_in, const int* in_sizes, int n_in,
                              void* d_out, int out_size, void* d_ws, size_t ws_size,
                              hipStream_t stream)
{
    const float* audios = (const float*)d_in[0];
    const float* mels   = (const float*)d_in[1];
    const float* w_mel0 = (const float*)d_in[2];
    const float* w_mel1 = (const float*)d_in[3];
    const float* w_mel2 = (const float*)d_in[4];
    const float* conv0w = (const float*)d_in[5];
    const float* bn0g = (const float*)d_in[6];
    const float* bn0b = (const float*)d_in[7];
    const float* bn0m = (const float*)d_in[8];
    const float* bn0v = (const float*)d_in[9];
    const float* r_w1   = (const float*)d_in[10];
    const float* r_bn1g = (const float*)d_in[11];
    const float* r_bn1b = (const float*)d_in[12];
    const float* r_bn1m = (const float*)d_in[13];
    const float* r_bn1v = (const float*)d_in[14];
    const float* r_w2   = (const float*)d_in[15];
    const float* r_bn2g = (const float*)d_in[16];
    const float* r_bn2b = (const float*)d_in[17];
    const float* r_bn2m = (const float*)d_in[18];
    const float* r_bn2v = (const float*)d_in[19];
    const float* mr_out_w = (const float*)d_in[20];
    const float* mr_out_b = (const float*)d_in[21];
    const float* Wi = (const float*)d_in[22];
    const float* bi = (const float*)d_in[23];
    const float* Wx0 = (const float*)d_in[24];
    const float* Wh0 = (const float*)d_in[25];
    const float* bx0 = (const float*)d_in[26];
    const float* bh0 = (const float*)d_in[27];
    const float* Wx1 = (const float*)d_in[28];
    const float* Wh1 = (const float*)d_in[29];
    const float* bx1 = (const float*)d_in[30];
    const float* bh1 = (const float*)d_in[31];
    const float* Wd0 = (const float*)d_in[32];
    const float* bd0 = (const float*)d_in[33];
    const float* Wd1 = (const float*)d_in[34];
    const float* bd1 = (const float*)d_in[35];
    const float* Wp = (const float*)d_in[36];
    const float* bp = (const float*)d_in[37];

    char* ws = (char*)d_ws;
    size_t off = 0;
    auto alloc = [&](size_t n) { size_t r = off; off += (n + 255) & ~(size_t)255; return r; };
    const size_t M = 4 * (size_t)T_SEQ;
    size_t xp_off = alloc(M * 1536 * 2);                     // bf16 xp; reused as f32 x3
    size_t x_off  = alloc(M * 512 * 4);                      // f32 x / x1 / x2 / x4
    size_t s1_off = alloc((size_t)4 * 176 * 80 * 4);
    size_t s2_off = alloc((size_t)4 * 1408 * 80 * 4);
    size_t s3_off = alloc((size_t)4 * 11264 * 80 * 4);
    size_t ca_off = alloc((size_t)160 * 128 * 4);
    size_t cf_off = alloc((size_t)160 * 128 * 4);
    size_t wp0_off = alloc((size_t)98304 * 8 * 2);           // packed Wh0
    size_t wp1_off = alloc((size_t)98304 * 8 * 2);           // packed Wh1
    size_t wt1_off = alloc((size_t)1536 * 576 * 2);          // Wt(Wx0)
    size_t wt2_off = alloc((size_t)1536 * 576 * 2);          // Wt(Wx1)
    size_t wt3_off = alloc((size_t)512 * 576 * 2);           // Wt(Wd0)
    size_t wt4_off = alloc((size_t)512 * 576 * 2);           // Wt(Wd1)
    size_t hp_off  = alloc(2 * 2048 * 4);                    // h pair buffers

    __hip_bfloat16* xp = (__hip_bfloat16*)(ws + xp_off);
    float* x3   = (float*)(ws + xp_off);
    float* xbuf = (float*)(ws + x_off);
    float* st1  = (float*)(ws + s1_off);
    float* st2  = (float*)(ws + s2_off);
    float* st3  = (float*)(ws + s3_off);
    float* conda = (float*)(ws + ca_off);
    float* condf = (float*)(ws + cf_off);
    unsigned short* wpack0 = (unsigned short*)(ws + wp0_off);
    unsigned short* wpack1 = (unsigned short*)(ws + wp1_off);
    unsigned short* wt1 = (unsigned short*)(ws + wt1_off);
    unsigned short* wt2 = (unsigned short*)(ws + wt2_off);
    unsigned short* wt3 = (unsigned short*)(ws + wt3_off);
    unsigned short* wt4 = (unsigned short*)(ws + wt4_off);
    unsigned int* hpair = (unsigned int*)(ws + hp_off);
    float* outp = (float*)d_out;

    // 0: weight packing
    pack_wh_kernel<<<384, 256, 0, stream>>>(Wh0, wpack0);
    pack_wh_kernel<<<384, 256, 0, stream>>>(Wh1, wpack1);
    pack_wt_kernel<<<(1536 * 576 + 255) / 256, 256, 0, stream>>>(Wx0, wt1, 512, 1536);
    pack_wt_kernel<<<(1536 * 576 + 255) / 256, 256, 0, stream>>>(Wx1, wt2, 544, 1536);
    pack_wt_kernel<<<(512 * 576 + 255) / 256, 256, 0, stream>>>(Wd0, wt3, 544, 512);
    pack_wt_kernel<<<(512 * 576 + 255) / 256, 256, 0, stream>>>(Wd1, wt4, 544, 512);

    // 1-3: mel upsampling
    upsample_kernel<<<(4 * 176 * 80 + 255) / 256, 256, 0, stream>>>(mels, st1, w_mel0, 4, 44, 176, 2, 9);
    upsample_kernel<<<(4 * 1408 * 80 + 255) / 256, 256, 0, stream>>>(st1, st2, w_mel1, 4, 176, 1408, 3, 17);
    upsample_kernel<<<(4 * 11264 * 80 + 255) / 256, 256, 0, stream>>>(st2, st3, w_mel2, 4, 1408, 11264, 3, 17);

    // 4-6: conditioning net
    conv0_kernel<<<160, 128, 0, stream>>>(mels, conv0w, bn0g, bn0b, bn0m, bn0v, conda);
    for (int i = 0; i < 10; ++i) {
        resblock_kernel<<<160, 128, 0, stream>>>(
            r_w1 + (size_t)i * 128 * 128, r_w2 + (size_t)i * 128 * 128,
            r_bn1g + i * 128, r_bn1b + i * 128, r_bn1m + i * 128, r_bn1v + i * 128,
            r_bn2g + i * 128, r_bn2b + i * 128, r_bn2m + i * 128, r_bn2v + i * 128,
            conda);
    }
    outmat_kernel<<<160, 128, 0, stream>>>(mr_out_w, mr_out_b, conda, condf);

    // 7: x = concat(audio, mels_up, a0) @ Wi + bi  (f32)
    gemm_big<<<dim3(8, 640), 256, 0, stream>>>(512, 113, Wi, bi, audios, st3, condf, xbuf);

    // 8: xp0 = x @ Wx0 + bx0 (+bh0 z/r)  [MFMA]
    gemm_mfma<<<dim3(12, 640), 256, 0, stream>>>(1, 512, wt1, bx0, bh0, condf,
        xbuf, nullptr, nullptr, xp);
    // 9: GRU0
    hipMemsetAsync(ws + hp_off, 0, 2 * 2048 * 4, stream);
    gru_mfma8<<<GRU_W, 512, 0, stream>>>(wpack0, bh0, xp, xbuf, hpair, T_SEQ);
    // 10: xp1 = concat(x1, a1) @ Wx1 + bx1 (+bh1 z/r)  [MFMA]
    gemm_mfma<<<dim3(12, 640), 256, 0, stream>>>(2, 544, wt2, bx1, bh1, condf,
        xbuf, nullptr, nullptr, xp);
    // 11: GRU1
    hipMemsetAsync(ws + hp_off, 0, 2 * 2048 * 4, stream);
    gru_mfma8<<<GRU_W, 512, 0, stream>>>(wpack1, bh1, xp, xbuf, hpair, T_SEQ);
    // 12: x3 = relu(concat(x2, a2) @ Wd0 + bd0) + x2  [MFMA]
    gemm_mfma<<<dim3(4, 640), 256, 0, stream>>>(3, 544, wt3, bd0, nullptr, condf,
        xbuf, xbuf, x3, nullptr);
    // 13: x4 = relu(concat(x3, a3) @ Wd1 + bd1) + x3  [MFMA]
    gemm_mfma<<<dim3(4, 640), 256, 0, stream>>>(4, 544, wt4, bd1, nullptr, condf,
        x3, x3, xbuf, nullptr);
    // 14: logits
    wp_kernel<<<5120, 256, 0, stream>>>(xbuf, Wp, bp, outp);
}

// Round 13
// 39522.214 us; speedup vs baseline: 1.2840x; 1.2840x over previous
//
#include <hip/hip_runtime.h>
#include <hip/hip_bf16.h>

#define T_SEQ 10240
#define GRU_W 8

typedef short bf16x8 __attribute__((ext_vector_type(8)));
typedef float f32x4 __attribute__((ext_vector_type(4)));

__device__ __forceinline__ float bf2f(unsigned short u) {
    return __uint_as_float(((unsigned int)u) << 16);
}
__device__ __forceinline__ unsigned short f2bf(float f) {
    __hip_bfloat16 h = __float2bfloat16(f);
    return *reinterpret_cast<unsigned short*>(&h);
}

// ---------------- mel upsampling ----------------
__global__ void upsample_kernel(const float* __restrict__ in, float* __restrict__ out,
                                const float* __restrict__ wk,
                                int B, int Tin, int Tout, int shift, int taps)
{
    int idx = blockIdx.x * blockDim.x + threadIdx.x;
    int total = B * Tout * 80;
    if (idx >= total) return;
    int m = idx % 80;
    int r = idx / 80;
    int t = r % Tout;
    int b = r / Tout;
    int s = taps >> 1;
    float acc = 0.f;
    for (int d = -s; d <= s; ++d) {
        int i = t + d;
        if (i >= 0 && i < Tout)
            acc += in[((size_t)b * Tin + (i >> shift)) * 80 + m] * wk[d + s];
    }
    out[idx] = acc;
}

// ---------------- conditioning net ----------------
__global__ __launch_bounds__(128) void conv0_kernel(
    const float* __restrict__ mels, const float* __restrict__ w,
    const float* __restrict__ g, const float* __restrict__ b,
    const float* __restrict__ m_, const float* __restrict__ v_,
    float* __restrict__ a)
{
    __shared__ float xin[400];
    int bt = blockIdx.x;
    int bb = bt / 40, t = bt % 40;
    int c = threadIdx.x;
    for (int idx = c; idx < 400; idx += 128)
        xin[idx] = mels[((size_t)bb * 44 + t + idx / 80) * 80 + (idx % 80)];
    __syncthreads();
    float s = 0.f;
    for (int q = 0; q < 400; ++q) s += xin[q] * w[q * 128 + c];
    s = (s - m_[c]) * rsqrtf(v_[c] + 1e-3f) * g[c] + b[c];
    a[bt * 128 + c] = fmaxf(s, 0.f);
}

__global__ __launch_bounds__(128) void resblock_kernel(
    const float* __restrict__ W1, const float* __restrict__ W2,
    const float* __restrict__ g1, const float* __restrict__ b1,
    const float* __restrict__ m1, const float* __restrict__ v1,
    const float* __restrict__ g2, const float* __restrict__ b2,
    const float* __restrict__ m2, const float* __restrict__ v2,
    float* __restrict__ a)
{
    __shared__ float ain[128], y1[128];
    int tok = blockIdx.x;
    int c = threadIdx.x;
    ain[c] = a[tok * 128 + c];
    __syncthreads();
    float s = 0.f;
    #pragma unroll 8
    for (int k = 0; k < 128; ++k) s += ain[k] * W1[k * 128 + c];
    s = (s - m1[c]) * rsqrtf(v1[c] + 1e-3f) * g1[c] + b1[c];
    y1[c] = fmaxf(s, 0.f);
    __syncthreads();
    float s2 = 0.f;
    #pragma unroll 8
    for (int k = 0; k < 128; ++k) s2 += y1[k] * W2[k * 128 + c];
    s2 = (s2 - m2[c]) * rsqrtf(v2[c] + 1e-3f) * g2[c] + b2[c];
    a[tok * 128 + c] = ain[c] + s2;
}

__global__ __launch_bounds__(128) void outmat_kernel(
    const float* __restrict__ W, const float* __restrict__ bias,
    const float* __restrict__ a, float* __restrict__ out)
{
    __shared__ float ain[128];
    int tok = blockIdx.x;
    int c = threadIdx.x;
    ain[c] = a[tok * 128 + c];
    __syncthreads();
    float s = 0.f;
    #pragma unroll 8
    for (int k = 0; k < 128; ++k) s += ain[k] * W[k * 128 + c];
    out[tok * 128 + c] = s + bias[c];
}

// ---------------- scalar GEMM (mode 0 only: Wi, K=113 gather) ----------------
__global__ __launch_bounds__(256) void gemm_big(
    int N, int K,
    const float* __restrict__ W, const float* __restrict__ bias1,
    const float* __restrict__ audio, const float* __restrict__ melsup,
    const float* __restrict__ cond, float* __restrict__ outF)
{
    __shared__ float As[16][68];
    __shared__ float Bs[16][68];
    const int tid = threadIdx.x;
    const int row0 = blockIdx.y * 64;
    const int col0 = blockIdx.x * 64;
    const int tx = tid & 15, ty = tid >> 4;
    float acc[4][4] = {};
    const int nkt = (K + 15) >> 4;
    for (int kt = 0; kt < nkt; ++kt) {
        const int kb = kt << 4;
        #pragma unroll
        for (int l = 0; l < 4; ++l) {
            int k = (tid >> 6) + l * 4;
            int m = tid & 63;
            float bv = 0.f;
            if (kb + k < K) bv = W[(size_t)(kb + k) * N + col0 + m];
            Bs[k][m] = bv;
            int row = row0 + m;
            int b = row / T_SEQ;
            int t = row - b * T_SEQ;
            int kk = kb + k;
            float av = 0.f;
            if (kk < K) {
                if (kk == 0) av = audio[(size_t)b * (T_SEQ + 1) + t];
                else if (kk < 81) av = melsup[((size_t)b * 11264 + 512 + t) * 80 + (kk - 1)];
                else av = cond[((size_t)b * 40 + (t >> 8)) * 128 + (kk - 81)];
            }
            As[k][m] = av;
        }
        __syncthreads();
        #pragma unroll
        for (int k = 0; k < 16; ++k) {
            float a0 = As[k][(ty << 2) + 0], a1 = As[k][(ty << 2) + 1];
            float a2 = As[k][(ty << 2) + 2], a3 = As[k][(ty << 2) + 3];
            float b0 = Bs[k][(tx << 2) + 0], b1 = Bs[k][(tx << 2) + 1];
            float b2 = Bs[k][(tx << 2) + 2], b3 = Bs[k][(tx << 2) + 3];
            acc[0][0] += a0 * b0; acc[0][1] += a0 * b1; acc[0][2] += a0 * b2; acc[0][3] += a0 * b3;
            acc[1][0] += a1 * b0; acc[1][1] += a1 * b1; acc[1][2] += a1 * b2; acc[1][3] += a1 * b3;
            acc[2][0] += a2 * b0; acc[2][1] += a2 * b1; acc[2][2] += a2 * b2; acc[2][3] += a2 * b3;
            acc[3][0] += a3 * b0; acc[3][1] += a3 * b1; acc[3][2] += a3 * b2; acc[3][3] += a3 * b3;
        }
        __syncthreads();
    }
    #pragma unroll
    for (int i = 0; i < 4; ++i) {
        int row = row0 + (ty << 2) + i;
        #pragma unroll
        for (int jt = 0; jt < 4; ++jt) {
            int col = col0 + (tx << 2) + jt;
            outF[(size_t)row * N + col] = acc[i][jt] + bias1[col];
        }
    }
}

// ---------------- pack W (f32 [K][N]) -> bf16 col-major [N][576], zero-padded K ----------------
__global__ __launch_bounds__(256) void pack_wt_kernel(const float* __restrict__ W,
                                                      unsigned short* __restrict__ out,
                                                      int K, int N)
{
    int idx = blockIdx.x * 256 + threadIdx.x;
    if (idx >= N * 576) return;
    int n = idx / 576, kp = idx % 576;
    out[idx] = (kp < K) ? f2bf(W[(size_t)kp * N + n]) : (unsigned short)0;
}

// ---------------- MFMA GEMM for modes 1-4 ----------------
__global__ __launch_bounds__(256) void gemm_mfma(
    int mode, int K,
    const unsigned short* __restrict__ Wt,   // [N][576] bf16
    const float* __restrict__ bias1,
    const float* __restrict__ bias2,
    const float* __restrict__ cond,
    const float* __restrict__ xA,            // (40960,512) f32
    const float* __restrict__ resid,
    float* __restrict__ outF,
    __hip_bfloat16* __restrict__ outB)
{
    __shared__ alignas(16) unsigned short A_sh[64][72];
    __shared__ alignas(16) unsigned short B_sh[128][72];
    const int tid = threadIdx.x;
    const int row0 = blockIdx.y * 64;
    const int col0 = blockIdx.x * 128;
    const int wv = tid >> 6, l = tid & 63;

    f32x4 acc[4][2] = {};
    const int nkt = (K + 63) >> 6;
    for (int it = 0; it < nkt; ++it) {
        const int kb = it << 6;
        {
            const int r = tid >> 2, q = tid & 3;
            const int row = row0 + r;
            unsigned short tmp[16];
            if (kb + 64 <= 512) {
                const float* src = xA + (size_t)row * 512 + kb + q * 16;
                #pragma unroll
                for (int e = 0; e < 16; e += 4) {
                    float4 v = *reinterpret_cast<const float4*>(src + e);
                    tmp[e + 0] = f2bf(v.x); tmp[e + 1] = f2bf(v.y);
                    tmp[e + 2] = f2bf(v.z); tmp[e + 3] = f2bf(v.w);
                }
            } else {
                const int b = row / T_SEQ, trow = row - b * T_SEQ;
                const int co = (mode == 2) ? 32 : (mode == 3) ? 64 : 96;
                const float* cp = cond + ((size_t)b * 40 + (trow >> 8)) * 128 + co;
                #pragma unroll
                for (int e = 0; e < 16; ++e) {
                    int k = kb + q * 16 + e;
                    float v = 0.f;
                    if (k < 512) v = xA[(size_t)row * 512 + k];
                    else if (k < K) v = cp[k - 512];
                    tmp[e] = f2bf(v);
                }
            }
            #pragma unroll
            for (int e = 0; e < 16; e += 8)
                *reinterpret_cast<uint4*>(&A_sh[r][q * 16 + e]) =
                    *reinterpret_cast<const uint4*>(&tmp[e]);
        }
        {
            const int c = tid >> 1, half = tid & 1;
            const unsigned short* src = Wt + (size_t)(col0 + c) * 576 + kb + half * 32;
            #pragma unroll
            for (int e = 0; e < 32; e += 8)
                *reinterpret_cast<uint4*>(&B_sh[c][half * 32 + e]) =
                    *reinterpret_cast<const uint4*>(src + e);
        }
        __syncthreads();
        const int rsel = l & 15, q = l >> 4;
        #pragma unroll
        for (int ks = 0; ks < 2; ++ks) {
            bf16x8 a[4], b[2];
            #pragma unroll
            for (int mf = 0; mf < 4; ++mf)
                a[mf] = *reinterpret_cast<const bf16x8*>(
                    &A_sh[mf * 16 + rsel][ks * 32 + q * 8]);
            #pragma unroll
            for (int nf = 0; nf < 2; ++nf)
                b[nf] = *reinterpret_cast<const bf16x8*>(
                    &B_sh[wv * 32 + nf * 16 + rsel][ks * 32 + q * 8]);
            #pragma unroll
            for (int mf = 0; mf < 4; ++mf)
                #pragma unroll
                for (int nf = 0; nf < 2; ++nf)
                    acc[mf][nf] = __builtin_amdgcn_mfma_f32_16x16x32_bf16(
                        a[mf], b[nf], acc[mf][nf], 0, 0, 0);
        }
        __syncthreads();
    }
    const int rsel = l & 15, q = l >> 4;
    #pragma unroll
    for (int mf = 0; mf < 4; ++mf) {
        #pragma unroll
        for (int nf = 0; nf < 2; ++nf) {
            #pragma unroll
            for (int i = 0; i < 4; ++i) {
                int row = row0 + mf * 16 + q * 4 + i;
                int col = col0 + wv * 32 + nf * 16 + rsel;
                float v = acc[mf][nf][i] + bias1[col];
                if (mode <= 2) {
                    if (col < 1024) v += bias2[col];
                    outB[(size_t)row * 1536 + col] = __float2bfloat16(v);
                } else {
                    v = fmaxf(v, 0.f) + resid[(size_t)row * 512 + col];
                    outF[(size_t)row * 512 + col] = v;
                }
            }
        }
    }
}

// ---------------- pack Wh -> per-wave MFMA B-fragments (r7 mapping) ----------------
__global__ __launch_bounds__(256) void pack_wh_kernel(const float* __restrict__ Wh,
                                                      unsigned short* __restrict__ out)
{
    int gid = blockIdx.x * 256 + threadIdx.x;     // < 98304
    int l = gid & 63;
    int idx = gid >> 6;
    int kt = idx & 15; idx >>= 4;
    int ntL = idx & 1; idx >>= 1;
    int w = idx % 6;
    int wg = idx / 6;
    int nt = 2 * w + ntL;
    int g = nt >> 2, u = nt & 3;
    int n = g * 512 + wg * 64 + u * 16 + (l & 15);
    int k0 = kt * 32 + (l >> 4) * 8;
    unsigned short* dst = out + (size_t)gid * 8;
    #pragma unroll
    for (int i = 0; i < 8; ++i)
        dst[i] = f2bf(Wh[(size_t)(k0 + i) * 1536 + n]);
}

// ---------------- 8-WG MFMA GRU (champion r11 structure) ----------------
// 512 thr = 8 waves. Waves 0-5: weights wf[2][16] (128 regs), MFMA 2 Ntiles.
// Waves 0-3 poll the h-ring (8 pairs each) + ds_write h_sh; tid<256 also
// computes gates after bar2 (one (batch,unit) per lane) + publish + xio.
// Waves 6-7: T14 staging of xp/xv (ds_write held t+1, then issue t+2 loads)
// into triple-buffered LDS -> no HBM latency inside the step.
// 2 barriers/step; h-ring = {tag16|bf16} 4B relaxed agent atomics, ping-pong.
__global__ __launch_bounds__(512, 2) void gru_mfma8(
    const unsigned short* __restrict__ wpack,
    const float* __restrict__ bh,
    const __hip_bfloat16* __restrict__ xp,      // (4*T,1536) bf16
    float* __restrict__ xio,                    // (4*T,512) f32 in x / out x+h
    unsigned int* __restrict__ hpair,           // [2][4][512] u32, memset 0
    int T)
{
    __shared__ alignas(16) unsigned short h_sh[16 * 512];      // 16 KB
    __shared__ alignas(16) unsigned short xp_sh[3][4][3][64];  // 4.5 KB
    __shared__ alignas(16) float xv_sh[3][4][64];              // 3 KB
    __shared__ alignas(16) float acc_sh[12][16][4];            // 3 KB

    const int tid = threadIdx.x;
    const int wg = blockIdx.x;
    const int w = tid >> 6;
    const int l = tid & 63;

    // zero h_sh (pad rows 4-15 must stay 0)
    {
        uint4* z = reinterpret_cast<uint4*>(h_sh);
        for (int i = tid; i < 1024; i += 512) z[i] = make_uint4(0, 0, 0, 0);
    }

    // weights (waves 0-5)
    bf16x8 wf[2][16];
    if (w < 6) {
        const bf16x8* wp = reinterpret_cast<const bf16x8*>(wpack);
        const int base = (wg * 6 + w) * 2 * 16 * 64;
        #pragma unroll
        for (int n = 0; n < 2; ++n)
            #pragma unroll
            for (int kt = 0; kt < 16; ++kt)
                wf[n][kt] = wp[base + (n * 16 + kt) * 64 + l];
    }

    float bhh = 0.f, hprev = 0.f;
    if (tid < 256) bhh = bh[1024 + wg * 64 + (tid & 63)];

    // ---- stage helpers (waves 6-7; xc in [0,128)) ----
    const int xc = tid - 384;
    uint4 hold_a = make_uint4(0, 0, 0, 0), hold_b = make_uint4(0, 0, 0, 0);
    #define STAGE_LOAD(c, t, dstv)                                              \
        { int c_ = (c);                                                         \
          if (c_ < 96) { int g_ = c_ / 32, b_ = (c_ % 32) / 8, s_ = c_ % 8;     \
            dstv = *reinterpret_cast<const uint4*>(                             \
                reinterpret_cast<const unsigned short*>(xp) +                   \
                ((size_t)b_ * T + (t)) * 1536 + g_ * 512 + wg * 64 + s_ * 8);   \
          } else { int d_ = c_ - 96, b_ = d_ >> 4, s_ = d_ & 15;                \
            dstv = *reinterpret_cast<const uint4*>(                             \
                xio + ((size_t)b_ * T + (t)) * 512 + wg * 64 + s_ * 4); } }
    #define STAGE_WRITE(c, buf, v)                                              \
        { int c_ = (c);                                                         \
          if (c_ < 96) { int g_ = c_ / 32, b_ = (c_ % 32) / 8, s_ = c_ % 8;     \
            *reinterpret_cast<uint4*>(&xp_sh[buf][b_][g_][s_ * 8]) = v;         \
          } else { int d_ = c_ - 96, b_ = d_ >> 4, s_ = d_ & 15;                \
            *reinterpret_cast<uint4*>(&xv_sh[buf][b_][s_ * 4]) = v; } }

    if (w >= 6) {
        uint4 v;
        STAGE_LOAD(xc, 0, v); STAGE_WRITE(xc, 0, v);
        if (xc < 32) { STAGE_LOAD(128 + xc, 0, v); STAGE_WRITE(128 + xc, 0, v); }
        if (T > 1) {
            STAGE_LOAD(xc, 1, hold_a);
            if (xc < 32) STAGE_LOAD(128 + xc, 1, hold_b);
        }
    }
    __syncthreads();

    const unsigned long long* hp64 = reinterpret_cast<const unsigned long long*>(hpair);
    const int pb = tid >> 6;                      // poll batch (waves 0-3)
    const int pchunk = (tid & 63) ^ (pb & 7);     // swizzled 16B chunk

    for (int t = 0; t < T; ++t) {
        const int cur = t & 1;
        const int bu = t % 3;

        if (tid < 256) {
            // ---- poll own 8 pairs (4 independent 8B loads) ----
            const unsigned long long* src = hp64 + (size_t)cur * 1024 + tid * 4;
            const unsigned tg = (unsigned)t & 0xffffu;
            unsigned long long u0 = __hip_atomic_load(src + 0, __ATOMIC_RELAXED, __HIP_MEMORY_SCOPE_AGENT);
            unsigned long long u1 = __hip_atomic_load(src + 1, __ATOMIC_RELAXED, __HIP_MEMORY_SCOPE_AGENT);
            unsigned long long u2 = __hip_atomic_load(src + 2, __ATOMIC_RELAXED, __HIP_MEMORY_SCOPE_AGENT);
            unsigned long long u3 = __hip_atomic_load(src + 3, __ATOMIC_RELAXED, __HIP_MEMORY_SCOPE_AGENT);
            while ((((unsigned)(u0 >> 16) & 0xffffu) != tg) | ((unsigned)(u0 >> 48) != tg) |
                   (((unsigned)(u1 >> 16) & 0xffffu) != tg) | ((unsigned)(u1 >> 48) != tg) |
                   (((unsigned)(u2 >> 16) & 0xffffu) != tg) | ((unsigned)(u2 >> 48) != tg) |
                   (((unsigned)(u3 >> 16) & 0xffffu) != tg) | ((unsigned)(u3 >> 48) != tg)) {
                __builtin_amdgcn_s_sleep(1);
                u0 = __hip_atomic_load(src + 0, __ATOMIC_RELAXED, __HIP_MEMORY_SCOPE_AGENT);
                u1 = __hip_atomic_load(src + 1, __ATOMIC_RELAXED, __HIP_MEMORY_SCOPE_AGENT);
                u2 = __hip_atomic_load(src + 2, __ATOMIC_RELAXED, __HIP_MEMORY_SCOPE_AGENT);
                u3 = __hip_atomic_load(src + 3, __ATOMIC_RELAXED, __HIP_MEMORY_SCOPE_AGENT);
            }
            uint4 wv;
            wv.x = (unsigned)(u0 & 0xffffull) | ((unsigned)((u0 >> 32) & 0xffffull) << 16);
            wv.y = (unsigned)(u1 & 0xffffull) | ((unsigned)((u1 >> 32) & 0xffffull) << 16);
            wv.z = (unsigned)(u2 & 0xffffull) | ((unsigned)((u2 >> 32) & 0xffffull) << 16);
            wv.w = (unsigned)(u3 & 0xffffull) | ((unsigned)((u3 >> 32) & 0xffffull) << 16);
            *reinterpret_cast<uint4*>(
                reinterpret_cast<char*>(h_sh) + pb * 1024 + pchunk * 16) = wv;
        } else if (w >= 6) {
            // ---- T14 staging: write held t+1, then issue t+2 loads ----
            if (t + 1 < T) {
                const int bn = (t + 1) % 3;
                STAGE_WRITE(xc, bn, hold_a);
                if (xc < 32) STAGE_WRITE(128 + xc, bn, hold_b);
            }
            if (t + 2 < T) {
                STAGE_LOAD(xc, t + 2, hold_a);
                if (xc < 32) STAGE_LOAD(128 + xc, t + 2, hold_b);
            }
        }
        __syncthreads();   // bar1: h_sh[t] + xp_sh[(t+1)%3] ordered

        if (w < 6) {
            f32x4 acc0 = {0, 0, 0, 0}, acc1 = {0, 0, 0, 0};
            const int rb = l & 15, q = l >> 4;
            #pragma unroll
            for (int kt = 0; kt < 16; ++kt) {
                bf16x8 afr = *reinterpret_cast<const bf16x8*>(
                    reinterpret_cast<const char*>(h_sh) + rb * 1024 +
                    ((((kt * 4 + q) ^ (rb & 7))) << 4));
                acc0 = __builtin_amdgcn_mfma_f32_16x16x32_bf16(afr, wf[0][kt], acc0, 0, 0, 0);
                acc1 = __builtin_amdgcn_mfma_f32_16x16x32_bf16(afr, wf[1][kt], acc1, 0, 0, 0);
            }
            if (l < 16) {
                *reinterpret_cast<f32x4*>(&acc_sh[2 * w][l][0]) = acc0;
                *reinterpret_cast<f32x4*>(&acc_sh[2 * w + 1][l][0]) = acc1;
            }
        }
        __syncthreads();   // bar2: acc_sh ready

        if (tid < 256) {
            const int b = tid >> 6, jl = tid & 63, j = wg * 64 + jl;
            const int u = jl >> 4, n16 = jl & 15;
            float az = acc_sh[u][n16][b];
            float ar = acc_sh[4 + u][n16][b];
            float ah = acc_sh[8 + u][n16][b];
            float xz = bf2f(xp_sh[bu][b][0][jl]);
            float xr = bf2f(xp_sh[bu][b][1][jl]);
            float xh = bf2f(xp_sh[bu][b][2][jl]);
            float xv = xv_sh[bu][b][jl];
            float z = 1.f / (1.f + __expf(-(xz + az)));
            float r = 1.f / (1.f + __expf(-(xr + ar)));
            float e2 = __expf(-2.f * (xh + r * (ah + bhh)));
            float hh = (1.f - e2) / (1.f + e2);
            float hn = z * hprev + (1.f - z) * hh;
            hprev = hn;
            unsigned hv = ((unsigned)((t + 1) & 0xffff) << 16) | (unsigned)f2bf(hn);
            __hip_atomic_store(hpair + (size_t)((t + 1) & 1) * 2048 + b * 512 + j, hv,
                               __ATOMIC_RELAXED, __HIP_MEMORY_SCOPE_AGENT);
            xio[((size_t)b * T + t) * 512 + j] = xv + hn;
        }
    }
    #undef STAGE_LOAD
    #undef STAGE_WRITE
}

// ---------------- final projection ----------------
__global__ __launch_bounds__(256) void wp_kernel(
    const float* __restrict__ x, const float* __restrict__ Wp,
    const float* __restrict__ bp, float* __restrict__ out)
{
    int r = threadIdx.x >> 5, c = threadIdx.x & 31;
    size_t row = (size_t)blockIdx.x * 8 + r;
    if (c >= 30) return;
    const float* xr = x + row * 512;
    float acc = 0.f;
    #pragma unroll 8
    for (int k = 0; k < 512; ++k) acc += xr[k] * Wp[k * 30 + c];
    out[row * 30 + c] = acc + bp[c];
}

extern "C" void kernel_launch(void* const* d_in, const int* in_sizes, int n_in,
                              void* d_out, int out_size, void* d_ws, size_t ws_size,
                              hipStream_t stream)
{
    const float* audios = (const float*)d_in[0];
    const float* mels   = (const float*)d_in[1];
    const float* w_mel0 = (const float*)d_in[2];
    const float* w_mel1 = (const float*)d_in[3];
    const float* w_mel2 = (const float*)d_in[4];
    const float* conv0w = (const float*)d_in[5];
    const float* bn0g = (const float*)d_in[6];
    const float* bn0b = (const float*)d_in[7];
    const float* bn0m = (const float*)d_in[8];
    const float* bn0v = (const float*)d_in[9];
    const float* r_w1   = (const float*)d_in[10];
    const float* r_bn1g = (const float*)d_in[11];
    const float* r_bn1b = (const float*)d_in[12];
    const float* r_bn1m = (const float*)d_in[13];
    const float* r_bn1v = (const float*)d_in[14];
    const float* r_w2   = (const float*)d_in[15];
    const float* r_bn2g = (const float*)d_in[16];
    const float* r_bn2b = (const float*)d_in[17];
    const float* r_bn2m = (const float*)d_in[18];
    const float* r_bn2v = (const float*)d_in[19];
    const float* mr_out_w = (const float*)d_in[20];
    const float* mr_out_b = (const float*)d_in[21];
    const float* Wi = (const float*)d_in[22];
    const float* bi = (const float*)d_in[23];
    const float* Wx0 = (const float*)d_in[24];
    const float* Wh0 = (const float*)d_in[25];
    const float* bx0 = (const float*)d_in[26];
    const float* bh0 = (const float*)d_in[27];
    const float* Wx1 = (const float*)d_in[28];
    const float* Wh1 = (const float*)d_in[29];
    const float* bx1 = (const float*)d_in[30];
    const float* bh1 = (const float*)d_in[31];
    const float* Wd0 = (const float*)d_in[32];
    const float* bd0 = (const float*)d_in[33];
    const float* Wd1 = (const float*)d_in[34];
    const float* bd1 = (const float*)d_in[35];
    const float* Wp = (const float*)d_in[36];
    const float* bp = (const float*)d_in[37];

    char* ws = (char*)d_ws;
    size_t off = 0;
    auto alloc = [&](size_t n) { size_t r = off; off += (n + 255) & ~(size_t)255; return r; };
    const size_t M = 4 * (size_t)T_SEQ;
    size_t xp_off = alloc(M * 1536 * 2);                     // bf16 xp; reused as f32 x3
    size_t x_off  = alloc(M * 512 * 4);                      // f32 x / x1 / x2 / x4
    size_t s1_off = alloc((size_t)4 * 176 * 80 * 4);
    size_t s2_off = alloc((size_t)4 * 1408 * 80 * 4);
    size_t s3_off = alloc((size_t)4 * 11264 * 80 * 4);
    size_t ca_off = alloc((size_t)160 * 128 * 4);
    size_t cf_off = alloc((size_t)160 * 128 * 4);
    size_t wp0_off = alloc((size_t)98304 * 8 * 2);           // packed Wh0
    size_t wp1_off = alloc((size_t)98304 * 8 * 2);           // packed Wh1
    size_t wt1_off = alloc((size_t)1536 * 576 * 2);          // Wt(Wx0)
    size_t wt2_off = alloc((size_t)1536 * 576 * 2);          // Wt(Wx1)
    size_t wt3_off = alloc((size_t)512 * 576 * 2);           // Wt(Wd0)
    size_t wt4_off = alloc((size_t)512 * 576 * 2);           // Wt(Wd1)
    size_t hp_off  = alloc(2 * 2048 * 4);                    // h pair buffers

    __hip_bfloat16* xp = (__hip_bfloat16*)(ws + xp_off);
    float* x3   = (float*)(ws + xp_off);
    float* xbuf = (float*)(ws + x_off);
    float* st1  = (float*)(ws + s1_off);
    float* st2  = (float*)(ws + s2_off);
    float* st3  = (float*)(ws + s3_off);
    float* conda = (float*)(ws + ca_off);
    float* condf = (float*)(ws + cf_off);
    unsigned short* wpack0 = (unsigned short*)(ws + wp0_off);
    unsigned short* wpack1 = (unsigned short*)(ws + wp1_off);
    unsigned short* wt1 = (unsigned short*)(ws + wt1_off);
    unsigned short* wt2 = (unsigned short*)(ws + wt2_off);
    unsigned short* wt3 = (unsigned short*)(ws + wt3_off);
    unsigned short* wt4 = (unsigned short*)(ws + wt4_off);
    unsigned int* hpair = (unsigned int*)(ws + hp_off);
    float* outp = (float*)d_out;

    // 0: weight packing
    pack_wh_kernel<<<384, 256, 0, stream>>>(Wh0, wpack0);
    pack_wh_kernel<<<384, 256, 0, stream>>>(Wh1, wpack1);
    pack_wt_kernel<<<(1536 * 576 + 255) / 256, 256, 0, stream>>>(Wx0, wt1, 512, 1536);
    pack_wt_kernel<<<(1536 * 576 + 255) / 256, 256, 0, stream>>>(Wx1, wt2, 544, 1536);
    pack_wt_kernel<<<(512 * 576 + 255) / 256, 256, 0, stream>>>(Wd0, wt3, 544, 512);
    pack_wt_kernel<<<(512 * 576 + 255) / 256, 256, 0, stream>>>(Wd1, wt4, 544, 512);

    // 1-3: mel upsampling
    upsample_kernel<<<(4 * 176 * 80 + 255) / 256, 256, 0, stream>>>(mels, st1, w_mel0, 4, 44, 176, 2, 9);
    upsample_kernel<<<(4 * 1408 * 80 + 255) / 256, 256, 0, stream>>>(st1, st2, w_mel1, 4, 176, 1408, 3, 17);
    upsample_kernel<<<(4 * 11264 * 80 + 255) / 256, 256, 0, stream>>>(st2, st3, w_mel2, 4, 1408, 11264, 3, 17);

    // 4-6: conditioning net
    conv0_kernel<<<160, 128, 0, stream>>>(mels, conv0w, bn0g, bn0b, bn0m, bn0v, conda);
    for (int i = 0; i < 10; ++i) {
        resblock_kernel<<<160, 128, 0, stream>>>(
            r_w1 + (size_t)i * 128 * 128, r_w2 + (size_t)i * 128 * 128,
            r_bn1g + i * 128, r_bn1b + i * 128, r_bn1m + i * 128, r_bn1v + i * 128,
            r_bn2g + i * 128, r_bn2b + i * 128, r_bn2m + i * 128, r_bn2v + i * 128,
            conda);
    }
    outmat_kernel<<<160, 128, 0, stream>>>(mr_out_w, mr_out_b, conda, condf);

    // 7: x = concat(audio, mels_up, a0) @ Wi + bi  (f32)
    gemm_big<<<dim3(8, 640), 256, 0, stream>>>(512, 113, Wi, bi, audios, st3, condf, xbuf);

    // 8: xp0 = x @ Wx0 + bx0 (+bh0 z/r)  [MFMA]
    gemm_mfma<<<dim3(12, 640), 256, 0, stream>>>(1, 512, wt1, bx0, bh0, condf,
        xbuf, nullptr, nullptr, xp);
    // 9: GRU0
    hipMemsetAsync(ws + hp_off, 0, 2 * 2048 * 4, stream);
    gru_mfma8<<<GRU_W, 512, 0, stream>>>(wpack0, bh0, xp, xbuf, hpair, T_SEQ);
    // 10: xp1 = concat(x1, a1) @ Wx1 + bx1 (+bh1 z/r)  [MFMA]
    gemm_mfma<<<dim3(12, 640), 256, 0, stream>>>(2, 544, wt2, bx1, bh1, condf,
        xbuf, nullptr, nullptr, xp);
    // 11: GRU1
    hipMemsetAsync(ws + hp_off, 0, 2 * 2048 * 4, stream);
    gru_mfma8<<<GRU_W, 512, 0, stream>>>(wpack1, bh1, xp, xbuf, hpair, T_SEQ);
    // 12: x3 = relu(concat(x2, a2) @ Wd0 + bd0) + x2  [MFMA]
    gemm_mfma<<<dim3(4, 640), 256, 0, stream>>>(3, 544, wt3, bd0, nullptr, condf,
        xbuf, xbuf, x3, nullptr);
    // 13: x4 = relu(concat(x3, a3) @ Wd1 + bd1) + x3  [MFMA]
    gemm_mfma<<<dim3(4, 640), 256, 0, stream>>>(4, 544, wt4, bd1, nullptr, condf,
        x3, x3, xbuf, nullptr);
    // 14: logits
    wp_kernel<<<5120, 256, 0, stream>>>(xbuf, Wp, bp, outp);
}